// Round 2
// baseline (2252.193 us; speedup 1.0000x reference)
//
#include <hip/hip_runtime.h>
#include <hip/hip_bf16.h>

// ---------------------------------------------------------------------------
// Patch embedding: conv3d stride=kernel=8 == per-token GEMV, + conv_b + pos
// grid: 1024 blocks (one per token), 256 threads
// ---------------------------------------------------------------------------
__global__ void patch_embed_kernel(const float* __restrict__ vol,
                                   const float* __restrict__ cw,
                                   const float* __restrict__ cb,
                                   const float* __restrict__ pos,
                                   float* __restrict__ x) {
  __shared__ float patch[512];
  int t = blockIdx.x;          // token 0..1023
  int b = t >> 9;
  int n = t & 511;
  int pd = n >> 6, ph = (n >> 3) & 7, pw = n & 7;
  int tid = threadIdx.x;
  const float* vbase = vol + ((size_t)b << 18);
  for (int l = tid; l < 512; l += 256) {
    int i = l >> 6, j = (l >> 3) & 7, k = l & 7;
    patch[l] = vbase[(pd * 8 + i) * 4096 + (ph * 8 + j) * 64 + (pw * 8 + k)];
  }
  __syncthreads();
  for (int c = tid; c < 768; c += 256) {
    const float* w = cw + c * 512;
    float acc = 0.f;
#pragma unroll 8
    for (int l = 0; l < 512; ++l) acc += w[l] * patch[l];
    x[t * 768 + c] = acc + cb[c] + pos[n * 768 + c];
  }
}

// ---------------------------------------------------------------------------
// LayerNorm over last dim (768). grid: 1024 rows, 256 threads.
// ---------------------------------------------------------------------------
__global__ void ln_kernel(const float* __restrict__ x, const float* __restrict__ w,
                          const float* __restrict__ b, float* __restrict__ out) {
  int row = blockIdx.x, tid = threadIdx.x;
  const float* xr = x + (size_t)row * 768;
  float s = 0.f, ss = 0.f;
  for (int i = tid; i < 768; i += 256) { float v = xr[i]; s += v; ss += v * v; }
  for (int off = 32; off; off >>= 1) {
    s += __shfl_xor(s, off);
    ss += __shfl_xor(ss, off);
  }
  __shared__ float sb[4], ssb[4];
  int wid = tid >> 6;
  if ((tid & 63) == 0) { sb[wid] = s; ssb[wid] = ss; }
  __syncthreads();
  s = sb[0] + sb[1] + sb[2] + sb[3];
  ss = ssb[0] + ssb[1] + ssb[2] + ssb[3];
  float m = s * (1.f / 768.f);
  float var = ss * (1.f / 768.f) - m * m;
  float r = rsqrtf(var + 1e-5f);
  for (int i = tid; i < 768; i += 256) {
    out[(size_t)row * 768 + i] = (xr[i] - m) * r * w[i] + b[i];
  }
}

// ---------------------------------------------------------------------------
// Tiled fp32 GEMM: C[M,N] = act(A[M,K] @ Bw[K,N] + bias) + res
// 64x64 tile, BK=16, 256 threads, 4x4 micro-tile. Dims multiples of 64/16.
// ---------------------------------------------------------------------------
template <int ACT, bool RES>
__global__ void gemm_kernel(const float* __restrict__ A, const float* __restrict__ Bw,
                            const float* __restrict__ bias, const float* __restrict__ res,
                            float* __restrict__ C, int M, int N, int K) {
  __shared__ float As[16][64];
  __shared__ float Bs[16][64];
  int tid = threadIdx.x;
  int m0 = blockIdx.y * 64, n0 = blockIdx.x * 64;
  int tx = tid & 15, ty = tid >> 4;
  int a_r = tid >> 2, a_k = (tid & 3) << 2;   // A tile: row 0..63, k 0,4,8,12
  int b_k = tid >> 4, b_n = (tid & 15) << 2;  // B tile: k 0..15, n step 4
  float acc[4][4] = {};
  for (int k0 = 0; k0 < K; k0 += 16) {
    float4 av = *(const float4*)&A[(size_t)(m0 + a_r) * K + k0 + a_k];
    As[a_k + 0][a_r] = av.x;
    As[a_k + 1][a_r] = av.y;
    As[a_k + 2][a_r] = av.z;
    As[a_k + 3][a_r] = av.w;
    float4 bv4 = *(const float4*)&Bw[(size_t)(k0 + b_k) * N + n0 + b_n];
    Bs[b_k][b_n + 0] = bv4.x;
    Bs[b_k][b_n + 1] = bv4.y;
    Bs[b_k][b_n + 2] = bv4.z;
    Bs[b_k][b_n + 3] = bv4.w;
    __syncthreads();
#pragma unroll
    for (int kk = 0; kk < 16; ++kk) {
      float4 a = *(const float4*)&As[kk][ty << 2];
      float4 bv = *(const float4*)&Bs[kk][tx << 2];
      float ar[4] = {a.x, a.y, a.z, a.w};
      float br[4] = {bv.x, bv.y, bv.z, bv.w};
#pragma unroll
      for (int i = 0; i < 4; ++i)
#pragma unroll
        for (int j = 0; j < 4; ++j) acc[i][j] += ar[i] * br[j];
    }
    __syncthreads();
  }
#pragma unroll
  for (int i = 0; i < 4; ++i) {
    int m = m0 + (ty << 2) + i;
#pragma unroll
    for (int j = 0; j < 4; ++j) {
      int n = n0 + (tx << 2) + j;
      float v = acc[i][j];
      if (bias) v += bias[n];
      if (ACT == 1) v = tanhf(v);
      if (RES) v += res[(size_t)m * N + n];
      C[(size_t)m * N + n] = v;
    }
  }
}

// ---------------------------------------------------------------------------
// Attention: one block per (b*12+h, qtile of 8). qkv fp32 [1024, 2304]
// layout per token: [q(768) | k(768) | v(768)], head h slice h*64..h*64+63.
// Full 8x512 score rows in LDS; K staged transposed (stride 65); V staged.
// ---------------------------------------------------------------------------
__global__ void attn_kernel(const float* __restrict__ qkv, float* __restrict__ o) {
  __shared__ float Qs[8][64];
  __shared__ float S[8][512];
  __shared__ float KV[64 * 65];
  int bh = blockIdx.x;  // 0..23
  int b = bh / 12, hh = bh % 12;
  int q0 = blockIdx.y * 8;
  int tid = threadIdx.x;
  int lane = tid & 63, wid = tid >> 6;
  const float* base = qkv + (size_t)b * 512 * 2304;

  // load Q tile, pre-scaled by 1/sqrt(64)
  for (int l = tid; l < 512; l += 256) {
    int q = l >> 6, d = l & 63;
    Qs[q][d] = base[(size_t)(q0 + q) * 2304 + hh * 64 + d] * 0.125f;
  }
  __syncthreads();

  // scores S = Q K^T
  for (int kt = 0; kt < 8; ++kt) {
    for (int l = tid; l < 4096; l += 256) {
      int kk = l >> 6, d = l & 63;
      KV[d * 65 + kk] = base[(size_t)(kt * 64 + kk) * 2304 + 768 + hh * 64 + d];
    }
    __syncthreads();
    for (int l = tid; l < 512; l += 256) {
      int q = l >> 6, kk = l & 63;
      float acc = 0.f;
#pragma unroll 16
      for (int d = 0; d < 64; ++d) acc += Qs[q][d] * KV[d * 65 + kk];
      S[q][kt * 64 + kk] = acc;
    }
    __syncthreads();
  }

  // softmax: wave wid handles rows 2*wid, 2*wid+1
  for (int rr = 0; rr < 2; ++rr) {
    int r = wid * 2 + rr;
    float mx = -1e30f;
    for (int i = lane; i < 512; i += 64) mx = fmaxf(mx, S[r][i]);
    for (int off = 32; off; off >>= 1) mx = fmaxf(mx, __shfl_xor(mx, off));
    float sum = 0.f;
    for (int i = lane; i < 512; i += 64) {
      float e = __expf(S[r][i] - mx);
      S[r][i] = e;
      sum += e;
    }
    for (int off = 32; off; off >>= 1) sum += __shfl_xor(sum, off);
    float inv = 1.f / sum;
    for (int i = lane; i < 512; i += 64) S[r][i] *= inv;
  }
  __syncthreads();

  // O = P V
  int dq = tid >> 6;  // handles rows dq and dq+4
  int d = tid & 63;
  float acc0 = 0.f, acc1 = 0.f;
  for (int kt = 0; kt < 8; ++kt) {
    for (int l = tid; l < 4096; l += 256) {
      int kk = l >> 6, dd = l & 63;
      KV[kk * 64 + dd] = base[(size_t)(kt * 64 + kk) * 2304 + 1536 + hh * 64 + dd];
    }
    __syncthreads();
#pragma unroll 16
    for (int kk = 0; kk < 64; ++kk) {
      float v = KV[kk * 64 + d];
      acc0 += S[dq][kt * 64 + kk] * v;
      acc1 += S[dq + 4][kt * 64 + kk] * v;
    }
    __syncthreads();
  }
  o[(size_t)(b * 512 + q0 + dq) * 768 + hh * 64 + d] = acc0;
  o[(size_t)(b * 512 + q0 + dq + 4) * 768 + hh * 64 + d] = acc1;
}

// ---------------------------------------------------------------------------
extern "C" void kernel_launch(void* const* d_in, const int* in_sizes, int n_in,
                              void* d_out, int out_size, void* d_ws, size_t ws_size,
                              hipStream_t stream) {
  const float* volume = (const float*)d_in[0];
  const float* conv_w = (const float*)d_in[1];
  const float* conv_b = (const float*)d_in[2];
  const float* pos    = (const float*)d_in[3];
  const float* ln1w   = (const float*)d_in[4];
  const float* ln1b   = (const float*)d_in[5];
  const float* wqkv   = (const float*)d_in[6];
  const float* wo     = (const float*)d_in[7];
  const float* bo     = (const float*)d_in[8];
  const float* ln2w   = (const float*)d_in[9];
  const float* ln2b   = (const float*)d_in[10];
  const float* w1     = (const float*)d_in[11];
  const float* b1     = (const float*)d_in[12];
  const float* w2     = (const float*)d_in[13];
  const float* b2     = (const float*)d_in[14];
  const float* lnfw   = (const float*)d_in[15];
  const float* lnfb   = (const float*)d_in[16];

  float* ws  = (float*)d_ws;
  float* x   = ws;                  // [1024, 768]
  float* h   = x + 1024 * 768;      // [1024, 768]
  float* qkv = h + 1024 * 768;      // [1024, 2304]
  float* o   = qkv + 1024 * 2304;   // [1024, 768]
  float* mlp = o + 1024 * 768;      // [1024, 3072]

  patch_embed_kernel<<<1024, 256, 0, stream>>>(volume, conv_w, conv_b, pos, x);

  for (int L = 0; L < 4; ++L) {
    ln_kernel<<<1024, 256, 0, stream>>>(x, ln1w + L * 768, ln1b + L * 768, h);
    gemm_kernel<0, false><<<dim3(36, 16), 256, 0, stream>>>(
        h, wqkv + (size_t)L * 768 * 2304, nullptr, nullptr, qkv, 1024, 2304, 768);
    attn_kernel<<<dim3(24, 64), 256, 0, stream>>>(qkv, o);
    gemm_kernel<0, true><<<dim3(12, 16), 256, 0, stream>>>(
        o, wo + (size_t)L * 768 * 768, bo + L * 768, x, x, 1024, 768, 768);
    ln_kernel<<<1024, 256, 0, stream>>>(x, ln2w + L * 768, ln2b + L * 768, h);
    gemm_kernel<1, false><<<dim3(48, 16), 256, 0, stream>>>(
        h, w1 + (size_t)L * 768 * 3072, b1 + L * 3072, nullptr, mlp, 1024, 3072, 768);
    gemm_kernel<0, true><<<dim3(12, 16), 256, 0, stream>>>(
        mlp, w2 + (size_t)L * 3072 * 768, b2 + L * 768, x, x, 1024, 768, 3072);
  }

  ln_kernel<<<1024, 256, 0, stream>>>(x, lnfw, lnfb, (float*)d_out);
}

// Round 3
// 1211.424 us; speedup vs baseline: 1.8591x; 1.8591x over previous
//
#include <hip/hip_runtime.h>
#include <hip/hip_bf16.h>

typedef __hip_bfloat16 bf16;
typedef short bf16x8 __attribute__((ext_vector_type(8)));
typedef float f32x4 __attribute__((ext_vector_type(4)));

__device__ __forceinline__ float b2f(bf16 v) { return __bfloat162float(v); }
__device__ __forceinline__ void storev(float* p, float v) { *p = v; }
__device__ __forceinline__ void storev(bf16* p, float v) { *p = __float2bfloat16(v); }

// ---------------------------------------------------------------------------
// im2col: volume fp32 -> patch matrix bf16 [1024 tokens][512]
// ---------------------------------------------------------------------------
__global__ void im2col_kernel(const float* __restrict__ vol, bf16* __restrict__ out) {
  int t = blockIdx.x;  // 0..1023
  int b = t >> 9, n = t & 511;
  int pd = n >> 6, ph = (n >> 3) & 7, pw = n & 7;
  const float* vb = vol + ((size_t)b << 18);
  for (int l = threadIdx.x; l < 512; l += 256) {
    int i = l >> 6, j = (l >> 3) & 7, k = l & 7;
    out[(size_t)t * 512 + l] =
        __float2bfloat16(vb[(pd * 8 + i) * 4096 + (ph * 8 + j) * 64 + (pw * 8 + k)]);
  }
}

// ---------------------------------------------------------------------------
// conv_w fp32 [768][512] -> bf16 same layout (already [N][K])
// ---------------------------------------------------------------------------
__global__ void convert_kernel(const float* __restrict__ in, bf16* __restrict__ out, int n) {
  int i = (blockIdx.x * 256 + threadIdx.x) * 4;
  if (i + 3 < n) {
    float4 v = *(const float4*)&in[i];
    out[i + 0] = __float2bfloat16(v.x);
    out[i + 1] = __float2bfloat16(v.y);
    out[i + 2] = __float2bfloat16(v.z);
    out[i + 3] = __float2bfloat16(v.w);
  }
}

// ---------------------------------------------------------------------------
// Per-layer weight transpose+convert: fp32 [R][C] -> bf16 [C][R] for all 4
// matrices of one layer in a single launch. Tiles 32x32 via LDS.
//   wqkv 768x2304 (1728 tiles) | wo 768x768 (576) | w1 768x3072 (2304)
//   | w2 3072x768 (2304)   -> grid 6912 blocks x 256 thr
// ---------------------------------------------------------------------------
__global__ __launch_bounds__(256) void transpose_all(
    const float* __restrict__ wqkv, const float* __restrict__ wo,
    const float* __restrict__ w1, const float* __restrict__ w2,
    bf16* __restrict__ tqkv, bf16* __restrict__ two,
    bf16* __restrict__ t1, bf16* __restrict__ t2) {
  int bid = blockIdx.x;
  const float* in;
  bf16* out;
  int R, C, tc, t0;
  if (bid < 1728)      { in = wqkv; out = tqkv; R = 768;  C = 2304; tc = 72; t0 = bid; }
  else if (bid < 2304) { in = wo;   out = two;  R = 768;  C = 768;  tc = 24; t0 = bid - 1728; }
  else if (bid < 4608) { in = w1;   out = t1;   R = 768;  C = 3072; tc = 96; t0 = bid - 2304; }
  else                 { in = w2;   out = t2;   R = 3072; C = 768;  tc = 24; t0 = bid - 4608; }
  int tr = t0 / tc, tcid = t0 % tc;
  int r0 = tr * 32, c0 = tcid * 32;
  __shared__ float tile[32][33];
  int tx = threadIdx.x & 31, ty = threadIdx.x >> 5;  // ty 0..7
#pragma unroll
  for (int yy = 0; yy < 4; ++yy)
    tile[ty + yy * 8][tx] = in[(size_t)(r0 + ty + yy * 8) * C + c0 + tx];
  __syncthreads();
#pragma unroll
  for (int yy = 0; yy < 4; ++yy) {
    int c = c0 + ty + yy * 8;
    out[(size_t)c * R + r0 + tx] = __float2bfloat16(tile[tx][ty + yy * 8]);
  }
}

// ---------------------------------------------------------------------------
// LayerNorm over last dim (768), fp32 in, OutT out. grid 1024 x 256.
// ---------------------------------------------------------------------------
template <typename OutT>
__global__ void ln_kernel(const float* __restrict__ x, const float* __restrict__ w,
                          const float* __restrict__ b, OutT* __restrict__ out) {
  int row = blockIdx.x, tid = threadIdx.x;
  const float* xr = x + (size_t)row * 768;
  float s = 0.f, ss = 0.f;
  for (int i = tid; i < 768; i += 256) { float v = xr[i]; s += v; ss += v * v; }
  for (int off = 32; off; off >>= 1) {
    s += __shfl_xor(s, off);
    ss += __shfl_xor(ss, off);
  }
  __shared__ float sb[4], ssb[4];
  int wid = tid >> 6;
  if ((tid & 63) == 0) { sb[wid] = s; ssb[wid] = ss; }
  __syncthreads();
  s = sb[0] + sb[1] + sb[2] + sb[3];
  ss = ssb[0] + ssb[1] + ssb[2] + ssb[3];
  float m = s * (1.f / 768.f);
  float var = ss * (1.f / 768.f) - m * m;
  float r = rsqrtf(var + 1e-5f);
  for (int i = tid; i < 768; i += 256)
    storev(out + (size_t)row * 768 + i, (xr[i] - m) * r * w[i] + b[i]);
}

// ---------------------------------------------------------------------------
// MFMA bf16 GEMM (B^T layout): C[M,N] = epi(A[M,K] @ Bt[N,K]^T)
// 256 thr = 4 waves (2x2), BK=64, LDS stride 72 (pad 8 -> 2-way only).
// EPI: 0 = plain -> bf16          (qkv)
//      1 = +bias +res -> f32      (proj, mlp2; res/C may alias = x)
//      2 = +bias, tanh -> bf16    (mlp1)
//      3 = +bias +pos -> f32      (patch embed; aux=pos[512][N])
// ---------------------------------------------------------------------------
template <int BM, int BN, int EPI>
__global__ __launch_bounds__(256) void mfma_gemm(
    const bf16* __restrict__ A, const bf16* __restrict__ Bt,
    const float* __restrict__ bias, const float* __restrict__ aux,
    void* __restrict__ Cout, int M, int N, int K) {
  constexpr int WTM = BM / 2, WTN = BN / 2;
  constexpr int MT = WTM / 16, NT = WTN / 16;
  constexpr int SK = 72;  // bf16 units; row = 144 B (16B-aligned, 2-way banks)
  __shared__ bf16 As[BM * SK];
  __shared__ bf16 Bs[BN * SK];
  int tid = threadIdx.x;
  int wave = tid >> 6, lane = tid & 63;
  int wm = wave >> 1, wn = wave & 1;
  int m15 = lane & 15, q = lane >> 4;
  int m0 = blockIdx.y * BM, n0 = blockIdx.x * BN;

  f32x4 acc[MT][NT];
#pragma unroll
  for (int i = 0; i < MT; ++i)
#pragma unroll
    for (int j = 0; j < NT; ++j) acc[i][j] = (f32x4){0.f, 0.f, 0.f, 0.f};

  for (int k0 = 0; k0 < K; k0 += 64) {
#pragma unroll
    for (int c = tid; c < BM * 8; c += 256) {
      int row = c >> 3, cc = c & 7;
      *(uint4*)&As[row * SK + cc * 8] =
          *(const uint4*)&A[(size_t)(m0 + row) * K + k0 + cc * 8];
    }
#pragma unroll
    for (int c = tid; c < BN * 8; c += 256) {
      int row = c >> 3, cc = c & 7;
      *(uint4*)&Bs[row * SK + cc * 8] =
          *(const uint4*)&Bt[(size_t)(n0 + row) * K + k0 + cc * 8];
    }
    __syncthreads();
#pragma unroll
    for (int s = 0; s < 2; ++s) {
      bf16x8 af[MT], bfr[NT];
#pragma unroll
      for (int i = 0; i < MT; ++i)
        af[i] = *(const bf16x8*)&As[(wm * WTM + i * 16 + m15) * SK + s * 32 + q * 8];
#pragma unroll
      for (int j = 0; j < NT; ++j)
        bfr[j] = *(const bf16x8*)&Bs[(wn * WTN + j * 16 + m15) * SK + s * 32 + q * 8];
#pragma unroll
      for (int i = 0; i < MT; ++i)
#pragma unroll
        for (int j = 0; j < NT; ++j)
          acc[i][j] = __builtin_amdgcn_mfma_f32_16x16x32_bf16(af[i], bfr[j], acc[i][j], 0, 0, 0);
    }
    __syncthreads();
  }

#pragma unroll
  for (int i = 0; i < MT; ++i) {
#pragma unroll
    for (int j = 0; j < NT; ++j) {
      int col = n0 + wn * WTN + j * 16 + m15;
      float bv = (EPI == 0) ? 0.f : bias[col];
#pragma unroll
      for (int r = 0; r < 4; ++r) {
        int row = m0 + wm * WTM + i * 16 + q * 4 + r;
        float v = acc[i][j][r] + bv;
        if (EPI == 2) v = tanhf(v);
        if (EPI == 1) v += aux[(size_t)row * N + col];
        if (EPI == 3) v += aux[(size_t)(row & 511) * N + col];
        if (EPI == 0 || EPI == 2)
          ((bf16*)Cout)[(size_t)row * N + col] = __float2bfloat16(v);
        else
          ((float*)Cout)[(size_t)row * N + col] = v;
      }
    }
  }
}

// ---------------------------------------------------------------------------
// Attention (fp32 VALU, bf16 in/out): block per (b*12+h, qtile of 8).
// qkv bf16 [1024, 2304]; per token [q|k|v], head slice h*64..h*64+63.
// ---------------------------------------------------------------------------
__global__ void attn_kernel(const bf16* __restrict__ qkv, bf16* __restrict__ o) {
  __shared__ float Qs[8][64];
  __shared__ float S[8][512];
  __shared__ float KV[64 * 65];
  int bh = blockIdx.x;
  int b = bh / 12, hh = bh % 12;
  int q0 = blockIdx.y * 8;
  int tid = threadIdx.x;
  int lane = tid & 63, wid = tid >> 6;
  const bf16* base = qkv + (size_t)b * 512 * 2304;

  for (int l = tid; l < 512; l += 256) {
    int q = l >> 6, d = l & 63;
    Qs[q][d] = b2f(base[(size_t)(q0 + q) * 2304 + hh * 64 + d]) * 0.125f;
  }
  __syncthreads();

  for (int kt = 0; kt < 8; ++kt) {
    for (int l = tid; l < 4096; l += 256) {
      int kk = l >> 6, d = l & 63;
      KV[d * 65 + kk] = b2f(base[(size_t)(kt * 64 + kk) * 2304 + 768 + hh * 64 + d]);
    }
    __syncthreads();
    for (int l = tid; l < 512; l += 256) {
      int q = l >> 6, kk = l & 63;
      float acc = 0.f;
#pragma unroll 16
      for (int d = 0; d < 64; ++d) acc += Qs[q][d] * KV[d * 65 + kk];
      S[q][kt * 64 + kk] = acc;
    }
    __syncthreads();
  }

  for (int rr = 0; rr < 2; ++rr) {
    int r = wid * 2 + rr;
    float mx = -1e30f;
    for (int i = lane; i < 512; i += 64) mx = fmaxf(mx, S[r][i]);
    for (int off = 32; off; off >>= 1) mx = fmaxf(mx, __shfl_xor(mx, off));
    float sum = 0.f;
    for (int i = lane; i < 512; i += 64) {
      float e = __expf(S[r][i] - mx);
      S[r][i] = e;
      sum += e;
    }
    for (int off = 32; off; off >>= 1) sum += __shfl_xor(sum, off);
    float inv = 1.f / sum;
    for (int i = lane; i < 512; i += 64) S[r][i] *= inv;
  }
  __syncthreads();

  int dq = tid >> 6;
  int d = tid & 63;
  float acc0 = 0.f, acc1 = 0.f;
  for (int kt = 0; kt < 8; ++kt) {
    for (int l = tid; l < 4096; l += 256) {
      int kk = l >> 6, dd = l & 63;
      KV[kk * 64 + dd] = b2f(base[(size_t)(kt * 64 + kk) * 2304 + 1536 + hh * 64 + dd]);
    }
    __syncthreads();
#pragma unroll 16
    for (int kk = 0; kk < 64; ++kk) {
      float v = KV[kk * 64 + d];
      acc0 += S[dq][kt * 64 + kk] * v;
      acc1 += S[dq + 4][kt * 64 + kk] * v;
    }
    __syncthreads();
  }
  o[(size_t)(b * 512 + q0 + dq) * 768 + hh * 64 + d] = __float2bfloat16(acc0);
  o[(size_t)(b * 512 + q0 + dq + 4) * 768 + hh * 64 + d] = __float2bfloat16(acc1);
}

// ---------------------------------------------------------------------------
extern "C" void kernel_launch(void* const* d_in, const int* in_sizes, int n_in,
                              void* d_out, int out_size, void* d_ws, size_t ws_size,
                              hipStream_t stream) {
  const float* volume = (const float*)d_in[0];
  const float* conv_w = (const float*)d_in[1];
  const float* conv_b = (const float*)d_in[2];
  const float* pos    = (const float*)d_in[3];
  const float* ln1w   = (const float*)d_in[4];
  const float* ln1b   = (const float*)d_in[5];
  const float* wqkv   = (const float*)d_in[6];
  const float* wo     = (const float*)d_in[7];
  const float* bo     = (const float*)d_in[8];
  const float* ln2w   = (const float*)d_in[9];
  const float* ln2b   = (const float*)d_in[10];
  const float* w1     = (const float*)d_in[11];
  const float* b1     = (const float*)d_in[12];
  const float* w2     = (const float*)d_in[13];
  const float* b2     = (const float*)d_in[14];
  const float* lnfw   = (const float*)d_in[15];
  const float* lnfb   = (const float*)d_in[16];

  // ws layout (30.7 MB total; <= 31.4 MB proven capacity)
  char* w = (char*)d_ws;
  float* x    = (float*)(w + 0);          // fp32 residual [1024][768]
  bf16* h     = (bf16*)(w + 3145728);     // ln output [1024][768]
  bf16* qkvb  = (bf16*)(w + 4718592);     // qkv [1024][2304]; aliases patchA
  bf16* patchA= qkvb;                     // im2col [1024][512]
  bf16* oact  = (bf16*)(w + 9437184);     // attn-o [1024][768] / mlp act [1024][3072]
  bf16* tqkv  = (bf16*)(w + 15728640);    // [2304][768]
  bf16* two   = (bf16*)(w + 19267584);    // [768][768]
  bf16* t1    = (bf16*)(w + 20447232);    // [3072][768]
  bf16* t2    = (bf16*)(w + 25165824);    // [768][3072]
  bf16* cwb   = (bf16*)(w + 29884416);    // conv_w bf16 [768][512]

  convert_kernel<<<384, 256, 0, stream>>>(conv_w, cwb, 768 * 512);
  im2col_kernel<<<1024, 256, 0, stream>>>(volume, patchA);
  // patch embed GEMM: x = patchA @ cwb^T + conv_b + pos
  mfma_gemm<64, 64, 3><<<dim3(12, 16), 256, 0, stream>>>(
      patchA, cwb, conv_b, pos, x, 1024, 768, 512);

  for (int L = 0; L < 4; ++L) {
    transpose_all<<<6912, 256, 0, stream>>>(
        wqkv + (size_t)L * 768 * 2304, wo + (size_t)L * 768 * 768,
        w1 + (size_t)L * 768 * 3072, w2 + (size_t)L * 3072 * 768,
        tqkv, two, t1, t2);
    ln_kernel<bf16><<<1024, 256, 0, stream>>>(x, ln1w + L * 768, ln1b + L * 768, h);
    mfma_gemm<64, 64, 0><<<dim3(36, 16), 256, 0, stream>>>(
        h, tqkv, nullptr, nullptr, qkvb, 1024, 2304, 768);
    attn_kernel<<<dim3(24, 64), 256, 0, stream>>>(qkvb, oact);
    mfma_gemm<64, 64, 1><<<dim3(12, 16), 256, 0, stream>>>(
        oact, two, bo + L * 768, x, x, 1024, 768, 768);
    ln_kernel<bf16><<<1024, 256, 0, stream>>>(x, ln2w + L * 768, ln2b + L * 768, h);
    mfma_gemm<128, 128, 2><<<dim3(24, 8), 256, 0, stream>>>(
        h, t1, b1 + L * 3072, nullptr, oact, 1024, 3072, 768);
    mfma_gemm<64, 64, 1><<<dim3(12, 16), 256, 0, stream>>>(
        oact, t2, b2 + L * 768, x, x, 1024, 768, 3072);
  }

  ln_kernel<float><<<1024, 256, 0, stream>>>(x, lnfw, lnfb, (float*)d_out);
}

// Round 4
// 967.272 us; speedup vs baseline: 2.3284x; 1.2524x over previous
//
#include <hip/hip_runtime.h>
#include <hip/hip_bf16.h>

typedef __hip_bfloat16 bf16;
typedef short bf16x8 __attribute__((ext_vector_type(8)));
typedef float f32x4 __attribute__((ext_vector_type(4)));

__device__ __forceinline__ float b2f(bf16 v) { return __bfloat162float(v); }
__device__ __forceinline__ void storev(float* p, float v) { *p = v; }
__device__ __forceinline__ void storev(bf16* p, float v) { *p = __float2bfloat16(v); }

// ---------------------------------------------------------------------------
// im2col: volume fp32 -> patch matrix bf16 [1024 tokens][512]
// ---------------------------------------------------------------------------
__global__ void im2col_kernel(const float* __restrict__ vol, bf16* __restrict__ out) {
  int t = blockIdx.x;
  int b = t >> 9, n = t & 511;
  int pd = n >> 6, ph = (n >> 3) & 7, pw = n & 7;
  const float* vb = vol + ((size_t)b << 18);
  for (int l = threadIdx.x; l < 512; l += 256) {
    int i = l >> 6, j = (l >> 3) & 7, k = l & 7;
    out[(size_t)t * 512 + l] =
        __float2bfloat16(vb[(pd * 8 + i) * 4096 + (ph * 8 + j) * 64 + (pw * 8 + k)]);
  }
}

__global__ void convert_kernel(const float* __restrict__ in, bf16* __restrict__ out, int n) {
  int i = (blockIdx.x * 256 + threadIdx.x) * 4;
  if (i + 3 < n) {
    float4 v = *(const float4*)&in[i];
    out[i + 0] = __float2bfloat16(v.x);
    out[i + 1] = __float2bfloat16(v.y);
    out[i + 2] = __float2bfloat16(v.z);
    out[i + 3] = __float2bfloat16(v.w);
  }
}

// ---------------------------------------------------------------------------
// Per-layer weight transpose+convert: fp32 [R][C] -> bf16 [C][R], 4 matrices.
// ---------------------------------------------------------------------------
__global__ __launch_bounds__(256) void transpose_all(
    const float* __restrict__ wqkv, const float* __restrict__ wo,
    const float* __restrict__ w1, const float* __restrict__ w2,
    bf16* __restrict__ tqkv, bf16* __restrict__ two,
    bf16* __restrict__ t1, bf16* __restrict__ t2) {
  int bid = blockIdx.x;
  const float* in;
  bf16* out;
  int R, C, tc, t0;
  if (bid < 1728)      { in = wqkv; out = tqkv; R = 768;  C = 2304; tc = 72; t0 = bid; }
  else if (bid < 2304) { in = wo;   out = two;  R = 768;  C = 768;  tc = 24; t0 = bid - 1728; }
  else if (bid < 4608) { in = w1;   out = t1;   R = 768;  C = 3072; tc = 96; t0 = bid - 2304; }
  else                 { in = w2;   out = t2;   R = 3072; C = 768;  tc = 24; t0 = bid - 4608; }
  int tr = t0 / tc, tcid = t0 % tc;
  int r0 = tr * 32, c0 = tcid * 32;
  __shared__ float tile[32][33];
  int tx = threadIdx.x & 31, ty = threadIdx.x >> 5;
#pragma unroll
  for (int yy = 0; yy < 4; ++yy)
    tile[ty + yy * 8][tx] = in[(size_t)(r0 + ty + yy * 8) * C + c0 + tx];
  __syncthreads();
#pragma unroll
  for (int yy = 0; yy < 4; ++yy) {
    int c = c0 + ty + yy * 8;
    out[(size_t)c * R + r0 + tx] = __float2bfloat16(tile[tx][ty + yy * 8]);
  }
}

// ---------------------------------------------------------------------------
// LayerNorm over last dim (768), fp32 in, OutT out. grid 1024 x 256.
// ---------------------------------------------------------------------------
template <typename OutT>
__global__ void ln_kernel(const float* __restrict__ x, const float* __restrict__ w,
                          const float* __restrict__ b, OutT* __restrict__ out) {
  int row = blockIdx.x, tid = threadIdx.x;
  const float* xr = x + (size_t)row * 768;
  float s = 0.f, ss = 0.f;
  for (int i = tid; i < 768; i += 256) { float v = xr[i]; s += v; ss += v * v; }
  for (int off = 32; off; off >>= 1) {
    s += __shfl_xor(s, off);
    ss += __shfl_xor(ss, off);
  }
  __shared__ float sb[4], ssb[4];
  int wid = tid >> 6;
  if ((tid & 63) == 0) { sb[wid] = s; ssb[wid] = ss; }
  __syncthreads();
  s = sb[0] + sb[1] + sb[2] + sb[3];
  ss = ssb[0] + ssb[1] + ssb[2] + ssb[3];
  float m = s * (1.f / 768.f);
  float var = ss * (1.f / 768.f) - m * m;
  float r = rsqrtf(var + 1e-5f);
  for (int i = tid; i < 768; i += 256)
    storev(out + (size_t)row * 768 + i, (xr[i] - m) * r * w[i] + b[i]);
}

// ---------------------------------------------------------------------------
// MFMA bf16 GEMM (B^T layout): C[M,N] = epi(A[M,K] @ Bt[N,K]^T)
// EPI: 0 plain->bf16 | 1 +bias+res->f32 | 2 +bias,tanh->bf16 | 3 +bias+pos->f32
//      4 qkv split: cols<1536 -> bf16 qk[row][1536]; cols>=1536 -> Vt[bh][d][tok]
// ---------------------------------------------------------------------------
template <int BM, int BN, int EPI>
__global__ __launch_bounds__(256) void mfma_gemm(
    const bf16* __restrict__ A, const bf16* __restrict__ Bt,
    const float* __restrict__ bias, const float* __restrict__ aux,
    bf16* __restrict__ vt,
    void* __restrict__ Cout, int M, int N, int K) {
  constexpr int WTM = BM / 2, WTN = BN / 2;
  constexpr int MT = WTM / 16, NT = WTN / 16;
  constexpr int SK = 72;
  __shared__ bf16 As[BM * SK];
  __shared__ bf16 Bs[BN * SK];
  int tid = threadIdx.x;
  int wave = tid >> 6, lane = tid & 63;
  int wm = wave >> 1, wn = wave & 1;
  int m15 = lane & 15, q = lane >> 4;
  int m0 = blockIdx.y * BM, n0 = blockIdx.x * BN;

  f32x4 acc[MT][NT];
#pragma unroll
  for (int i = 0; i < MT; ++i)
#pragma unroll
    for (int j = 0; j < NT; ++j) acc[i][j] = (f32x4){0.f, 0.f, 0.f, 0.f};

  for (int k0 = 0; k0 < K; k0 += 64) {
#pragma unroll
    for (int c = tid; c < BM * 8; c += 256) {
      int row = c >> 3, cc = c & 7;
      *(uint4*)&As[row * SK + cc * 8] =
          *(const uint4*)&A[(size_t)(m0 + row) * K + k0 + cc * 8];
    }
#pragma unroll
    for (int c = tid; c < BN * 8; c += 256) {
      int row = c >> 3, cc = c & 7;
      *(uint4*)&Bs[row * SK + cc * 8] =
          *(const uint4*)&Bt[(size_t)(n0 + row) * K + k0 + cc * 8];
    }
    __syncthreads();
#pragma unroll
    for (int s = 0; s < 2; ++s) {
      bf16x8 af[MT], bfr[NT];
#pragma unroll
      for (int i = 0; i < MT; ++i)
        af[i] = *(const bf16x8*)&As[(wm * WTM + i * 16 + m15) * SK + s * 32 + q * 8];
#pragma unroll
      for (int j = 0; j < NT; ++j)
        bfr[j] = *(const bf16x8*)&Bs[(wn * WTN + j * 16 + m15) * SK + s * 32 + q * 8];
#pragma unroll
      for (int i = 0; i < MT; ++i)
#pragma unroll
        for (int j = 0; j < NT; ++j)
          acc[i][j] = __builtin_amdgcn_mfma_f32_16x16x32_bf16(af[i], bfr[j], acc[i][j], 0, 0, 0);
    }
    __syncthreads();
  }

#pragma unroll
  for (int i = 0; i < MT; ++i) {
#pragma unroll
    for (int j = 0; j < NT; ++j) {
      int col = n0 + wn * WTN + j * 16 + m15;
      if (EPI == 4) {
        if (col < 1536) {
#pragma unroll
          for (int r = 0; r < 4; ++r) {
            int row = m0 + wm * WTM + i * 16 + q * 4 + r;
            ((bf16*)Cout)[(size_t)row * 1536 + col] = __float2bfloat16(acc[i][j][r]);
          }
        } else {
          int row0 = m0 + wm * WTM + i * 16 + q * 4;
          int cl = col - 1536;
          int hh = cl >> 6, dd = cl & 63;
          int bb = row0 >> 9, tok = row0 & 511;
          bf16 pk[4];
#pragma unroll
          for (int r = 0; r < 4; ++r) pk[r] = __float2bfloat16(acc[i][j][r]);
          *(uint2*)&vt[((size_t)(bb * 12 + hh) * 64 + dd) * 512 + tok] = *(uint2*)pk;
        }
      } else {
        float bv = (EPI == 0) ? 0.f : bias[col];
#pragma unroll
        for (int r = 0; r < 4; ++r) {
          int row = m0 + wm * WTM + i * 16 + q * 4 + r;
          float v = acc[i][j][r] + bv;
          if (EPI == 2) v = tanhf(v);
          if (EPI == 1) v += aux[(size_t)row * N + col];
          if (EPI == 3) v += aux[(size_t)(row & 511) * N + col];
          if (EPI == 0 || EPI == 2)
            ((bf16*)Cout)[(size_t)row * N + col] = __float2bfloat16(v);
          else
            ((float*)Cout)[(size_t)row * N + col] = v;
        }
      }
    }
  }
}

// ---------------------------------------------------------------------------
// MFMA attention. Block = (b*12+h, 32-query tile), 128 thr = 2 waves.
// qk bf16 [1024][1536] (Q | K per token); Vt bf16 [24][64 d][512 tok].
// Phase 1: S^T tiles = mfma(A=K-frag, B=Q-frag)  (lane = q-col, regs = k-rows)
// Softmax in-reg (tiles x regs) + shfl_xor(16/32) over quads.
// P -> LDS [q][k] (= A-frag layout), O = mfma(A=P, B=Vt-chunk).
// ---------------------------------------------------------------------------
__global__ __launch_bounds__(128) void attn_mfma(const bf16* __restrict__ qk,
                                                 const bf16* __restrict__ Vt,
                                                 bf16* __restrict__ o) {
  constexpr int PS = 520;  // P row stride (bf16): 1040 B, 16B-aligned
  __shared__ bf16 KVs[64 * 72];
  __shared__ bf16 P[32 * PS];
  int bh = blockIdx.x;
  int b = bh / 12, hh = bh % 12;
  int q0 = blockIdx.y * 32;
  int tid = threadIdx.x;
  int wave = tid >> 6, lane = tid & 63;
  int n15 = lane & 15, quad = lane >> 4;
  const bf16* qkb = qk + (size_t)b * 512 * 1536;
  int ql = wave * 16 + n15;  // local q (0..31) this lane's column

  // Q fragments (B-operand), loop-invariant over k
  const bf16* qp = qkb + (size_t)(q0 + ql) * 1536 + hh * 64 + quad * 8;
  bf16x8 qf0 = *(const bf16x8*)qp;
  bf16x8 qf1 = *(const bf16x8*)(qp + 32);

  f32x4 S[32];
#pragma unroll
  for (int i = 0; i < 32; ++i) S[i] = (f32x4){0.f, 0.f, 0.f, 0.f};

  const bf16* kbase = qkb + 768 + hh * 64;
#pragma unroll
  for (int kc = 0; kc < 8; ++kc) {
    __syncthreads();
#pragma unroll
    for (int c = tid; c < 512; c += 128) {
      int r = c >> 3, cc = c & 7;
      *(uint4*)&KVs[r * 72 + cc * 8] =
          *(const uint4*)&kbase[(size_t)(kc * 64 + r) * 1536 + cc * 8];
    }
    __syncthreads();
#pragma unroll
    for (int t = 0; t < 4; ++t) {
      int idx = kc * 4 + t;
      bf16x8 a0 = *(const bf16x8*)&KVs[(t * 16 + n15) * 72 + quad * 8];
      bf16x8 a1 = *(const bf16x8*)&KVs[(t * 16 + n15) * 72 + 32 + quad * 8];
      S[idx] = __builtin_amdgcn_mfma_f32_16x16x32_bf16(a0, qf0, S[idx], 0, 0, 0);
      S[idx] = __builtin_amdgcn_mfma_f32_16x16x32_bf16(a1, qf1, S[idx], 0, 0, 0);
    }
  }

  // softmax over k for this lane's q-column
  float mx = -1e30f;
#pragma unroll
  for (int i = 0; i < 32; ++i)
#pragma unroll
    for (int r = 0; r < 4; ++r) { S[i][r] *= 0.125f; mx = fmaxf(mx, S[i][r]); }
  mx = fmaxf(mx, __shfl_xor(mx, 16));
  mx = fmaxf(mx, __shfl_xor(mx, 32));
  float sum = 0.f;
#pragma unroll
  for (int i = 0; i < 32; ++i)
#pragma unroll
    for (int r = 0; r < 4; ++r) { float e = __expf(S[i][r] - mx); S[i][r] = e; sum += e; }
  sum += __shfl_xor(sum, 16);
  sum += __shfl_xor(sum, 32);
  float inv = 1.f / sum;

  // write P[q][k] bf16 (4 consecutive k per tile -> one 8B store)
#pragma unroll
  for (int i = 0; i < 32; ++i) {
    bf16 pk[4];
#pragma unroll
    for (int r = 0; r < 4; ++r) pk[r] = __float2bfloat16(S[i][r] * inv);
    *(uint2*)&P[(size_t)ql * PS + i * 16 + quad * 4] = *(uint2*)pk;
  }

  // O = P V via Vt chunks
  f32x4 oacc[4];
#pragma unroll
  for (int dt = 0; dt < 4; ++dt) oacc[dt] = (f32x4){0.f, 0.f, 0.f, 0.f};
  const bf16* vtb = Vt + (size_t)bh * 64 * 512;
  for (int kc = 0; kc < 8; ++kc) {
    __syncthreads();
#pragma unroll
    for (int c = tid; c < 512; c += 128) {
      int r = c >> 3, cc = c & 7;
      *(uint4*)&KVs[r * 72 + cc * 8] =
          *(const uint4*)&vtb[(size_t)r * 512 + kc * 64 + cc * 8];
    }
    __syncthreads();
    bf16x8 p0 = *(const bf16x8*)&P[(size_t)ql * PS + kc * 64 + quad * 8];
    bf16x8 p1 = *(const bf16x8*)&P[(size_t)ql * PS + kc * 64 + 32 + quad * 8];
#pragma unroll
    for (int dt = 0; dt < 4; ++dt) {
      bf16x8 v0 = *(const bf16x8*)&KVs[(dt * 16 + n15) * 72 + quad * 8];
      bf16x8 v1 = *(const bf16x8*)&KVs[(dt * 16 + n15) * 72 + 32 + quad * 8];
      oacc[dt] = __builtin_amdgcn_mfma_f32_16x16x32_bf16(p0, v0, oacc[dt], 0, 0, 0);
      oacc[dt] = __builtin_amdgcn_mfma_f32_16x16x32_bf16(p1, v1, oacc[dt], 0, 0, 0);
    }
  }

  // epilogue: O rows = q (quad*4+r), cols = d (n15) per d-tile
#pragma unroll
  for (int dt = 0; dt < 4; ++dt)
#pragma unroll
    for (int r = 0; r < 4; ++r) {
      int tok = q0 + wave * 16 + quad * 4 + r;
      o[((size_t)b * 512 + tok) * 768 + hh * 64 + dt * 16 + n15] =
          __float2bfloat16(oacc[dt][r]);
    }
}

// ---------------------------------------------------------------------------
extern "C" void kernel_launch(void* const* d_in, const int* in_sizes, int n_in,
                              void* d_out, int out_size, void* d_ws, size_t ws_size,
                              hipStream_t stream) {
  const float* volume = (const float*)d_in[0];
  const float* conv_w = (const float*)d_in[1];
  const float* conv_b = (const float*)d_in[2];
  const float* pos    = (const float*)d_in[3];
  const float* ln1w   = (const float*)d_in[4];
  const float* ln1b   = (const float*)d_in[5];
  const float* wqkv   = (const float*)d_in[6];
  const float* wo     = (const float*)d_in[7];
  const float* bo     = (const float*)d_in[8];
  const float* ln2w   = (const float*)d_in[9];
  const float* ln2b   = (const float*)d_in[10];
  const float* w1     = (const float*)d_in[11];
  const float* b1     = (const float*)d_in[12];
  const float* w2     = (const float*)d_in[13];
  const float* b2     = (const float*)d_in[14];
  const float* lnfw   = (const float*)d_in[15];
  const float* lnfb   = (const float*)d_in[16];

  // ws layout (30.7 MB)
  char* w = (char*)d_ws;
  float* x    = (float*)(w + 0);          // fp32 residual [1024][768]
  bf16* h     = (bf16*)(w + 3145728);     // ln output [1024][768]
  bf16* qk    = (bf16*)(w + 4718592);     // Q|K [1024][1536]; aliases patchA
  bf16* patchA= qk;                       // im2col [1024][512]
  bf16* Vt    = (bf16*)(w + 7864320);     // V^T [24][64][512]
  bf16* oact  = (bf16*)(w + 9437184);     // attn-o [1024][768] / mlp act [1024][3072]
  bf16* tqkv  = (bf16*)(w + 15728640);    // [2304][768]
  bf16* two   = (bf16*)(w + 19267584);    // [768][768]
  bf16* t1    = (bf16*)(w + 20447232);    // [3072][768]
  bf16* t2    = (bf16*)(w + 25165824);    // [768][3072]
  bf16* cwb   = (bf16*)(w + 29884416);    // conv_w bf16 [768][512]

  convert_kernel<<<384, 256, 0, stream>>>(conv_w, cwb, 768 * 512);
  im2col_kernel<<<1024, 256, 0, stream>>>(volume, patchA);
  mfma_gemm<64, 64, 3><<<dim3(12, 16), 256, 0, stream>>>(
      patchA, cwb, conv_b, pos, nullptr, x, 1024, 768, 512);

  for (int L = 0; L < 4; ++L) {
    transpose_all<<<6912, 256, 0, stream>>>(
        wqkv + (size_t)L * 768 * 2304, wo + (size_t)L * 768 * 768,
        w1 + (size_t)L * 768 * 3072, w2 + (size_t)L * 3072 * 768,
        tqkv, two, t1, t2);
    ln_kernel<bf16><<<1024, 256, 0, stream>>>(x, ln1w + L * 768, ln1b + L * 768, h);
    mfma_gemm<64, 64, 4><<<dim3(36, 16), 256, 0, stream>>>(
        h, tqkv, nullptr, nullptr, Vt, qk, 1024, 2304, 768);
    attn_mfma<<<dim3(24, 16), 128, 0, stream>>>(qk, Vt, oact);
    mfma_gemm<64, 64, 1><<<dim3(12, 16), 256, 0, stream>>>(
        oact, two, bo + L * 768, x, nullptr, x, 1024, 768, 768);
    ln_kernel<bf16><<<1024, 256, 0, stream>>>(x, ln2w + L * 768, ln2b + L * 768, h);
    mfma_gemm<128, 128, 2><<<dim3(24, 8), 256, 0, stream>>>(
        h, t1, b1 + L * 3072, nullptr, nullptr, oact, 1024, 3072, 768);
    mfma_gemm<64, 64, 1><<<dim3(12, 16), 256, 0, stream>>>(
        oact, t2, b2 + L * 768, x, nullptr, x, 1024, 768, 3072);
  }

  ln_kernel<float><<<1024, 256, 0, stream>>>(x, lnfw, lnfb, (float*)d_out);
}

// Round 5
// 706.246 us; speedup vs baseline: 3.1890x; 1.3696x over previous
//
#include <hip/hip_runtime.h>
#include <hip/hip_bf16.h>

typedef __hip_bfloat16 bf16;
typedef short bf16x8 __attribute__((ext_vector_type(8)));
typedef float f32x4 __attribute__((ext_vector_type(4)));

__device__ __forceinline__ float b2f(bf16 v) { return __bfloat162float(v); }
__device__ __forceinline__ void storev(float* p, float v) { *p = v; }
__device__ __forceinline__ void storev(bf16* p, float v) { *p = __float2bfloat16(v); }

// ---------------------------------------------------------------------------
// im2col: volume fp32 -> patch matrix bf16 [1024 tokens][512]
// ---------------------------------------------------------------------------
__global__ void im2col_kernel(const float* __restrict__ vol, bf16* __restrict__ out) {
  int t = blockIdx.x;
  int b = t >> 9, n = t & 511;
  int pd = n >> 6, ph = (n >> 3) & 7, pw = n & 7;
  const float* vb = vol + ((size_t)b << 18);
  for (int l = threadIdx.x; l < 512; l += 256) {
    int i = l >> 6, j = (l >> 3) & 7, k = l & 7;
    out[(size_t)t * 512 + l] =
        __float2bfloat16(vb[(pd * 8 + i) * 4096 + (ph * 8 + j) * 64 + (pw * 8 + k)]);
  }
}

__global__ void convert_kernel(const float* __restrict__ in, bf16* __restrict__ out, int n) {
  int i = (blockIdx.x * 256 + threadIdx.x) * 4;
  if (i + 3 < n) {
    float4 v = *(const float4*)&in[i];
    out[i + 0] = __float2bfloat16(v.x);
    out[i + 1] = __float2bfloat16(v.y);
    out[i + 2] = __float2bfloat16(v.z);
    out[i + 3] = __float2bfloat16(v.w);
  }
}

// ---------------------------------------------------------------------------
// Per-layer weight transpose+convert: fp32 [R][C] -> bf16 [C][R], 4 matrices,
// 64x64 tiles. qkv 12x36=432 | wo 12x12=144 | w1 12x48=576 | w2 48x12=576
// ---------------------------------------------------------------------------
__global__ __launch_bounds__(256) void transpose_all(
    const float* __restrict__ wqkv, const float* __restrict__ wo,
    const float* __restrict__ w1, const float* __restrict__ w2,
    bf16* __restrict__ tqkv, bf16* __restrict__ two,
    bf16* __restrict__ t1, bf16* __restrict__ t2) {
  int bid = blockIdx.x;
  const float* in;
  bf16* out;
  int R, C, tc, t0;
  if (bid < 432)       { in = wqkv; out = tqkv; R = 768;  C = 2304; tc = 36; t0 = bid; }
  else if (bid < 576)  { in = wo;   out = two;  R = 768;  C = 768;  tc = 12; t0 = bid - 432; }
  else if (bid < 1152) { in = w1;   out = t1;   R = 768;  C = 3072; tc = 48; t0 = bid - 576; }
  else                 { in = w2;   out = t2;   R = 3072; C = 768;  tc = 12; t0 = bid - 1152; }
  int r0 = (t0 / tc) * 64, c0 = (t0 % tc) * 64;
  __shared__ float tile[64][65];
  int tx = threadIdx.x & 15, ty = threadIdx.x >> 4;
#pragma unroll
  for (int yy = 0; yy < 4; ++yy) {
    float4 v = *(const float4*)&in[(size_t)(r0 + ty + yy * 16) * C + c0 + tx * 4];
    tile[ty + yy * 16][tx * 4 + 0] = v.x;
    tile[ty + yy * 16][tx * 4 + 1] = v.y;
    tile[ty + yy * 16][tx * 4 + 2] = v.z;
    tile[ty + yy * 16][tx * 4 + 3] = v.w;
  }
  __syncthreads();
  int cl = threadIdx.x >> 3;       // 0..31
  int rb = (threadIdx.x & 7) * 8;  // 0..56
#pragma unroll
  for (int half = 0; half < 2; ++half) {
    int c = cl + half * 32;
    bf16 pk[8];
#pragma unroll
    for (int e = 0; e < 8; ++e) pk[e] = __float2bfloat16(tile[rb + e][c]);
    *(uint4*)&out[(size_t)(c0 + c) * R + r0 + rb] = *(uint4*)pk;
  }
}

// ---------------------------------------------------------------------------
// LayerNorm over last dim (768), fp32 in, OutT out. grid 1024 x 256.
// ---------------------------------------------------------------------------
template <typename OutT>
__global__ void ln_kernel(const float* __restrict__ x, const float* __restrict__ w,
                          const float* __restrict__ b, OutT* __restrict__ out) {
  int row = blockIdx.x, tid = threadIdx.x;
  const float* xr = x + (size_t)row * 768;
  float s = 0.f, ss = 0.f;
  for (int i = tid; i < 768; i += 256) { float v = xr[i]; s += v; ss += v * v; }
  for (int off = 32; off; off >>= 1) {
    s += __shfl_xor(s, off);
    ss += __shfl_xor(ss, off);
  }
  __shared__ float sb[4], ssb[4];
  int wid = tid >> 6;
  if ((tid & 63) == 0) { sb[wid] = s; ssb[wid] = ss; }
  __syncthreads();
  s = sb[0] + sb[1] + sb[2] + sb[3];
  ss = ssb[0] + ssb[1] + ssb[2] + ssb[3];
  float m = s * (1.f / 768.f);
  float var = ss * (1.f / 768.f) - m * m;
  float r = rsqrtf(var + 1e-5f);
  for (int i = tid; i < 768; i += 256)
    storev(out + (size_t)row * 768 + i, (xr[i] - m) * r * w[i] + b[i]);
}

// ---------------------------------------------------------------------------
// MFMA bf16 GEMM (B^T layout): C[M,N] = epi(A[M,K] @ Bt[N,K]^T)
// Split-K via blockIdx.z (EPI=5 only: atomic accumulate into fp32 C).
// EPI: 0 plain->bf16 | 2 +bias,tanh->bf16 | 3 +bias+pos->f32
//      4 qkv split: cols<1536 -> bf16 qk[row][1536]; cols>=1536 -> Vt[bh][d][tok]
//      5 atomicAdd into f32 C (+bias when blockIdx.z==0)
// ---------------------------------------------------------------------------
template <int BM, int BN, int EPI>
__global__ __launch_bounds__(256) void mfma_gemm(
    const bf16* __restrict__ A, const bf16* __restrict__ Bt,
    const float* __restrict__ bias, const float* __restrict__ aux,
    bf16* __restrict__ vt,
    void* __restrict__ Cout, int M, int N, int K) {
  constexpr int WTM = BM / 2, WTN = BN / 2;
  constexpr int MT = WTM / 16, NT = WTN / 16;
  constexpr int SK = 72;
  __shared__ bf16 As[BM * SK];
  __shared__ bf16 Bs[BN * SK];
  int tid = threadIdx.x;
  int wave = tid >> 6, lane = tid & 63;
  int wm = wave >> 1, wn = wave & 1;
  int m15 = lane & 15, q = lane >> 4;
  int m0 = blockIdx.y * BM, n0 = blockIdx.x * BN;
  int kspan = K / gridDim.z;
  int kbeg = blockIdx.z * kspan, kend = kbeg + kspan;

  f32x4 acc[MT][NT];
#pragma unroll
  for (int i = 0; i < MT; ++i)
#pragma unroll
    for (int j = 0; j < NT; ++j) acc[i][j] = (f32x4){0.f, 0.f, 0.f, 0.f};

  for (int k0 = kbeg; k0 < kend; k0 += 64) {
#pragma unroll
    for (int c = tid; c < BM * 8; c += 256) {
      int row = c >> 3, cc = c & 7;
      *(uint4*)&As[row * SK + cc * 8] =
          *(const uint4*)&A[(size_t)(m0 + row) * K + k0 + cc * 8];
    }
#pragma unroll
    for (int c = tid; c < BN * 8; c += 256) {
      int row = c >> 3, cc = c & 7;
      *(uint4*)&Bs[row * SK + cc * 8] =
          *(const uint4*)&Bt[(size_t)(n0 + row) * K + k0 + cc * 8];
    }
    __syncthreads();
#pragma unroll
    for (int s = 0; s < 2; ++s) {
      bf16x8 af[MT], bfr[NT];
#pragma unroll
      for (int i = 0; i < MT; ++i)
        af[i] = *(const bf16x8*)&As[(wm * WTM + i * 16 + m15) * SK + s * 32 + q * 8];
#pragma unroll
      for (int j = 0; j < NT; ++j)
        bfr[j] = *(const bf16x8*)&Bs[(wn * WTN + j * 16 + m15) * SK + s * 32 + q * 8];
#pragma unroll
      for (int i = 0; i < MT; ++i)
#pragma unroll
        for (int j = 0; j < NT; ++j)
          acc[i][j] = __builtin_amdgcn_mfma_f32_16x16x32_bf16(af[i], bfr[j], acc[i][j], 0, 0, 0);
    }
    __syncthreads();
  }

#pragma unroll
  for (int i = 0; i < MT; ++i) {
#pragma unroll
    for (int j = 0; j < NT; ++j) {
      int col = n0 + wn * WTN + j * 16 + m15;
      if (EPI == 4) {
        if (col < 1536) {
#pragma unroll
          for (int r = 0; r < 4; ++r) {
            int row = m0 + wm * WTM + i * 16 + q * 4 + r;
            ((bf16*)Cout)[(size_t)row * 1536 + col] = __float2bfloat16(acc[i][j][r]);
          }
        } else {
          int row0 = m0 + wm * WTM + i * 16 + q * 4;
          int cl = col - 1536;
          int hh = cl >> 6, dd = cl & 63;
          int bb = row0 >> 9, tok = row0 & 511;
          bf16 pk[4];
#pragma unroll
          for (int r = 0; r < 4; ++r) pk[r] = __float2bfloat16(acc[i][j][r]);
          *(uint2*)&vt[((size_t)(bb * 12 + hh) * 64 + dd) * 512 + tok] = *(uint2*)pk;
        }
      } else if (EPI == 5) {
        float bv = (blockIdx.z == 0) ? bias[col] : 0.f;
#pragma unroll
        for (int r = 0; r < 4; ++r) {
          int row = m0 + wm * WTM + i * 16 + q * 4 + r;
          unsafeAtomicAdd(&((float*)Cout)[(size_t)row * N + col], acc[i][j][r] + bv);
        }
      } else {
        float bv = (EPI == 0) ? 0.f : bias[col];
#pragma unroll
        for (int r = 0; r < 4; ++r) {
          int row = m0 + wm * WTM + i * 16 + q * 4 + r;
          float v = acc[i][j][r] + bv;
          if (EPI == 2) v = tanhf(v);
          if (EPI == 3) v += aux[(size_t)(row & 511) * N + col];
          if (EPI == 0 || EPI == 2)
            ((bf16*)Cout)[(size_t)row * N + col] = __float2bfloat16(v);
          else
            ((float*)Cout)[(size_t)row * N + col] = v;
        }
      }
    }
  }
}

// ---------------------------------------------------------------------------
// MFMA attention. Block = (b*12+h, 32-query tile), 128 thr = 2 waves.
// ---------------------------------------------------------------------------
__global__ __launch_bounds__(128) void attn_mfma(const bf16* __restrict__ qk,
                                                 const bf16* __restrict__ Vt,
                                                 bf16* __restrict__ o) {
  constexpr int PS = 520;
  __shared__ bf16 KVs[64 * 72];
  __shared__ bf16 P[32 * PS];
  int bh = blockIdx.x;
  int b = bh / 12, hh = bh % 12;
  int q0 = blockIdx.y * 32;
  int tid = threadIdx.x;
  int wave = tid >> 6, lane = tid & 63;
  int n15 = lane & 15, quad = lane >> 4;
  const bf16* qkb = qk + (size_t)b * 512 * 1536;
  int ql = wave * 16 + n15;

  const bf16* qp = qkb + (size_t)(q0 + ql) * 1536 + hh * 64 + quad * 8;
  bf16x8 qf0 = *(const bf16x8*)qp;
  bf16x8 qf1 = *(const bf16x8*)(qp + 32);

  f32x4 S[32];
#pragma unroll
  for (int i = 0; i < 32; ++i) S[i] = (f32x4){0.f, 0.f, 0.f, 0.f};

  const bf16* kbase = qkb + 768 + hh * 64;
#pragma unroll
  for (int kc = 0; kc < 8; ++kc) {
    __syncthreads();
#pragma unroll
    for (int c = tid; c < 512; c += 128) {
      int r = c >> 3, cc = c & 7;
      *(uint4*)&KVs[r * 72 + cc * 8] =
          *(const uint4*)&kbase[(size_t)(kc * 64 + r) * 1536 + cc * 8];
    }
    __syncthreads();
#pragma unroll
    for (int t = 0; t < 4; ++t) {
      int idx = kc * 4 + t;
      bf16x8 a0 = *(const bf16x8*)&KVs[(t * 16 + n15) * 72 + quad * 8];
      bf16x8 a1 = *(const bf16x8*)&KVs[(t * 16 + n15) * 72 + 32 + quad * 8];
      S[idx] = __builtin_amdgcn_mfma_f32_16x16x32_bf16(a0, qf0, S[idx], 0, 0, 0);
      S[idx] = __builtin_amdgcn_mfma_f32_16x16x32_bf16(a1, qf1, S[idx], 0, 0, 0);
    }
  }

  float mx = -1e30f;
#pragma unroll
  for (int i = 0; i < 32; ++i)
#pragma unroll
    for (int r = 0; r < 4; ++r) { S[i][r] *= 0.125f; mx = fmaxf(mx, S[i][r]); }
  mx = fmaxf(mx, __shfl_xor(mx, 16));
  mx = fmaxf(mx, __shfl_xor(mx, 32));
  float sum = 0.f;
#pragma unroll
  for (int i = 0; i < 32; ++i)
#pragma unroll
    for (int r = 0; r < 4; ++r) { float e = __expf(S[i][r] - mx); S[i][r] = e; sum += e; }
  sum += __shfl_xor(sum, 16);
  sum += __shfl_xor(sum, 32);
  float inv = 1.f / sum;

#pragma unroll
  for (int i = 0; i < 32; ++i) {
    bf16 pk[4];
#pragma unroll
    for (int r = 0; r < 4; ++r) pk[r] = __float2bfloat16(S[i][r] * inv);
    *(uint2*)&P[(size_t)ql * PS + i * 16 + quad * 4] = *(uint2*)pk;
  }

  f32x4 oacc[4];
#pragma unroll
  for (int dt = 0; dt < 4; ++dt) oacc[dt] = (f32x4){0.f, 0.f, 0.f, 0.f};
  const bf16* vtb = Vt + (size_t)bh * 64 * 512;
  for (int kc = 0; kc < 8; ++kc) {
    __syncthreads();
#pragma unroll
    for (int c = tid; c < 512; c += 128) {
      int r = c >> 3, cc = c & 7;
      *(uint4*)&KVs[r * 72 + cc * 8] =
          *(const uint4*)&vtb[(size_t)r * 512 + kc * 64 + cc * 8];
    }
    __syncthreads();
    bf16x8 p0 = *(const bf16x8*)&P[(size_t)ql * PS + kc * 64 + quad * 8];
    bf16x8 p1 = *(const bf16x8*)&P[(size_t)ql * PS + kc * 64 + 32 + quad * 8];
#pragma unroll
    for (int dt = 0; dt < 4; ++dt) {
      bf16x8 v0 = *(const bf16x8*)&KVs[(dt * 16 + n15) * 72 + quad * 8];
      bf16x8 v1 = *(const bf16x8*)&KVs[(dt * 16 + n15) * 72 + 32 + quad * 8];
      oacc[dt] = __builtin_amdgcn_mfma_f32_16x16x32_bf16(p0, v0, oacc[dt], 0, 0, 0);
      oacc[dt] = __builtin_amdgcn_mfma_f32_16x16x32_bf16(p1, v1, oacc[dt], 0, 0, 0);
    }
  }

#pragma unroll
  for (int dt = 0; dt < 4; ++dt)
#pragma unroll
    for (int r = 0; r < 4; ++r) {
      int tok = q0 + wave * 16 + quad * 4 + r;
      o[((size_t)b * 512 + tok) * 768 + hh * 64 + dt * 16 + n15] =
          __float2bfloat16(oacc[dt][r]);
    }
}

// ---------------------------------------------------------------------------
extern "C" void kernel_launch(void* const* d_in, const int* in_sizes, int n_in,
                              void* d_out, int out_size, void* d_ws, size_t ws_size,
                              hipStream_t stream) {
  const float* volume = (const float*)d_in[0];
  const float* conv_w = (const float*)d_in[1];
  const float* conv_b = (const float*)d_in[2];
  const float* pos    = (const float*)d_in[3];
  const float* ln1w   = (const float*)d_in[4];
  const float* ln1b   = (const float*)d_in[5];
  const float* wqkv   = (const float*)d_in[6];
  const float* wo     = (const float*)d_in[7];
  const float* bo     = (const float*)d_in[8];
  const float* ln2w   = (const float*)d_in[9];
  const float* ln2b   = (const float*)d_in[10];
  const float* w1     = (const float*)d_in[11];
  const float* b1     = (const float*)d_in[12];
  const float* w2     = (const float*)d_in[13];
  const float* b2     = (const float*)d_in[14];
  const float* lnfw   = (const float*)d_in[15];
  const float* lnfb   = (const float*)d_in[16];

  // ws layout (30.7 MB)
  char* w = (char*)d_ws;
  float* x    = (float*)(w + 0);          // fp32 residual [1024][768]
  bf16* h     = (bf16*)(w + 3145728);     // ln output [1024][768]
  bf16* qk    = (bf16*)(w + 4718592);     // Q|K [1024][1536]; aliases patchA
  bf16* patchA= qk;                       // im2col [1024][512]
  bf16* Vt    = (bf16*)(w + 7864320);     // V^T [24][64][512]
  bf16* oact  = (bf16*)(w + 9437184);     // attn-o [1024][768] / mlp act [1024][3072]
  bf16* tqkv  = (bf16*)(w + 15728640);    // [2304][768]
  bf16* two   = (bf16*)(w + 19267584);    // [768][768]
  bf16* t1    = (bf16*)(w + 20447232);    // [3072][768]
  bf16* t2    = (bf16*)(w + 25165824);    // [768][3072]
  bf16* cwb   = (bf16*)(w + 29884416);    // conv_w bf16 [768][512]

  convert_kernel<<<384, 256, 0, stream>>>(conv_w, cwb, 768 * 512);
  im2col_kernel<<<1024, 256, 0, stream>>>(volume, patchA);
  mfma_gemm<64, 64, 3><<<dim3(12, 16), 256, 0, stream>>>(
      patchA, cwb, conv_b, pos, nullptr, x, 1024, 768, 512);

  for (int L = 0; L < 4; ++L) {
    transpose_all<<<1728, 256, 0, stream>>>(
        wqkv + (size_t)L * 768 * 2304, wo + (size_t)L * 768 * 768,
        w1 + (size_t)L * 768 * 3072, w2 + (size_t)L * 3072 * 768,
        tqkv, two, t1, t2);
    ln_kernel<bf16><<<1024, 256, 0, stream>>>(x, ln1w + L * 768, ln1b + L * 768, h);
    mfma_gemm<64, 64, 4><<<dim3(36, 16), 256, 0, stream>>>(
        h, tqkv, nullptr, nullptr, Vt, qk, 1024, 2304, 768);
    attn_mfma<<<dim3(24, 16), 128, 0, stream>>>(qk, Vt, oact);
    mfma_gemm<64, 64, 5><<<dim3(12, 16, 2), 256, 0, stream>>>(
        oact, two, bo + L * 768, nullptr, nullptr, x, 1024, 768, 768);
    ln_kernel<bf16><<<1024, 256, 0, stream>>>(x, ln2w + L * 768, ln2b + L * 768, h);
    mfma_gemm<64, 64, 2><<<dim3(48, 16), 256, 0, stream>>>(
        h, t1, b1 + L * 3072, nullptr, nullptr, oact, 1024, 3072, 768);
    mfma_gemm<64, 64, 5><<<dim3(12, 16, 4), 256, 0, stream>>>(
        oact, t2, b2 + L * 768, nullptr, nullptr, x, 1024, 768, 3072);
  }

  ln_kernel<float><<<1024, 256, 0, stream>>>(x, lnfw, lnfb, (float*)d_out);
}

// Round 6
// 519.536 us; speedup vs baseline: 4.3350x; 1.3594x over previous
//
#include <hip/hip_runtime.h>
#include <hip/hip_bf16.h>

typedef __hip_bfloat16 bf16;
typedef short bf16x8 __attribute__((ext_vector_type(8)));
typedef float f32x4 __attribute__((ext_vector_type(4)));

__device__ __forceinline__ float b2f(bf16 v) { return __bfloat162float(v); }
__device__ __forceinline__ void storev(float* p, float v) { *p = v; }
__device__ __forceinline__ void storev(bf16* p, float v) { *p = __float2bfloat16(v); }

// async global->LDS, 16B per lane. LDS dest must be wave base + lane*16.
__device__ __forceinline__ void gl2lds16(const bf16* g, bf16* l) {
  __builtin_amdgcn_global_load_lds(
      (const __attribute__((address_space(1))) unsigned int*)g,
      (__attribute__((address_space(3))) unsigned int*)l, 16, 0, 0);
}

// ---------------------------------------------------------------------------
// im2col: volume fp32 -> patch matrix bf16 [1024 tokens][512]
// ---------------------------------------------------------------------------
__global__ void im2col_kernel(const float* __restrict__ vol, bf16* __restrict__ out) {
  int t = blockIdx.x;
  int b = t >> 9, n = t & 511;
  int pd = n >> 6, ph = (n >> 3) & 7, pw = n & 7;
  const float* vb = vol + ((size_t)b << 18);
  for (int l = threadIdx.x; l < 512; l += 256) {
    int i = l >> 6, j = (l >> 3) & 7, k = l & 7;
    out[(size_t)t * 512 + l] =
        __float2bfloat16(vb[(pd * 8 + i) * 4096 + (ph * 8 + j) * 64 + (pw * 8 + k)]);
  }
}

__global__ void convert_kernel(const float* __restrict__ in, bf16* __restrict__ out, int n) {
  int i = (blockIdx.x * 256 + threadIdx.x) * 4;
  if (i + 3 < n) {
    float4 v = *(const float4*)&in[i];
    out[i + 0] = __float2bfloat16(v.x);
    out[i + 1] = __float2bfloat16(v.y);
    out[i + 2] = __float2bfloat16(v.z);
    out[i + 3] = __float2bfloat16(v.w);
  }
}

// ---------------------------------------------------------------------------
// Weight transpose+convert for ALL 4 layers in one launch: fp32 [R][C] ->
// bf16 [C][R]. grid (1728, 4): y = layer. 64x64 tiles.
// ---------------------------------------------------------------------------
__global__ __launch_bounds__(256) void transpose_all(
    const float* __restrict__ wqkv, const float* __restrict__ wo,
    const float* __restrict__ w1, const float* __restrict__ w2,
    bf16* __restrict__ tqkv, bf16* __restrict__ two,
    bf16* __restrict__ t1, bf16* __restrict__ t2) {
  int bid = blockIdx.x;
  size_t L = blockIdx.y;
  const float* in;
  bf16* out;
  int R, C, tc, t0;
  if (bid < 432)       { in = wqkv + L * 768 * 2304; out = tqkv + L * 768 * 2304; R = 768;  C = 2304; tc = 36; t0 = bid; }
  else if (bid < 576)  { in = wo + L * 768 * 768;    out = two + L * 768 * 768;   R = 768;  C = 768;  tc = 12; t0 = bid - 432; }
  else if (bid < 1152) { in = w1 + L * 768 * 3072;   out = t1 + L * 768 * 3072;   R = 768;  C = 3072; tc = 48; t0 = bid - 576; }
  else                 { in = w2 + L * 3072 * 768;   out = t2 + L * 3072 * 768;   R = 3072; C = 768;  tc = 12; t0 = bid - 1152; }
  int r0 = (t0 / tc) * 64, c0 = (t0 % tc) * 64;
  __shared__ float tile[64][65];
  int tx = threadIdx.x & 15, ty = threadIdx.x >> 4;
#pragma unroll
  for (int yy = 0; yy < 4; ++yy) {
    float4 v = *(const float4*)&in[(size_t)(r0 + ty + yy * 16) * C + c0 + tx * 4];
    tile[ty + yy * 16][tx * 4 + 0] = v.x;
    tile[ty + yy * 16][tx * 4 + 1] = v.y;
    tile[ty + yy * 16][tx * 4 + 2] = v.z;
    tile[ty + yy * 16][tx * 4 + 3] = v.w;
  }
  __syncthreads();
  int cl = threadIdx.x >> 3;
  int rb = (threadIdx.x & 7) * 8;
#pragma unroll
  for (int half = 0; half < 2; ++half) {
    int c = cl + half * 32;
    bf16 pk[8];
#pragma unroll
    for (int e = 0; e < 8; ++e) pk[e] = __float2bfloat16(tile[rb + e][c]);
    *(uint4*)&out[(size_t)(c0 + c) * R + r0 + rb] = *(uint4*)pk;
  }
}

// ---------------------------------------------------------------------------
// LayerNorm over last dim (768), fp32 in, OutT out. grid 1024 x 256.
// ---------------------------------------------------------------------------
template <typename OutT>
__global__ void ln_kernel(const float* __restrict__ x, const float* __restrict__ w,
                          const float* __restrict__ b, OutT* __restrict__ out) {
  int row = blockIdx.x, tid = threadIdx.x;
  const float* xr = x + (size_t)row * 768;
  float s = 0.f, ss = 0.f;
  for (int i = tid; i < 768; i += 256) { float v = xr[i]; s += v; ss += v * v; }
  for (int off = 32; off; off >>= 1) {
    s += __shfl_xor(s, off);
    ss += __shfl_xor(ss, off);
  }
  __shared__ float sb[4], ssb[4];
  int wid = tid >> 6;
  if ((tid & 63) == 0) { sb[wid] = s; ssb[wid] = ss; }
  __syncthreads();
  s = sb[0] + sb[1] + sb[2] + sb[3];
  ss = ssb[0] + ssb[1] + ssb[2] + ssb[3];
  float m = s * (1.f / 768.f);
  float var = ss * (1.f / 768.f) - m * m;
  float r = rsqrtf(var + 1e-5f);
  for (int i = tid; i < 768; i += 256)
    storev(out + (size_t)row * 768 + i, (xr[i] - m) * r * w[i] + b[i]);
}

// ---------------------------------------------------------------------------
// MFMA bf16 GEMM (B^T layout), global_load_lds staging, unpadded SK=64.
// EPI: 0 plain->bf16 | 2 +bias,tanh->bf16 | 3 +bias+pos->f32
//      4 qkv split | 5 atomicAdd into f32 C (+bias when z==0)
// ---------------------------------------------------------------------------
template <int BM, int BN, int EPI>
__global__ __launch_bounds__(256) void mfma_gemm(
    const bf16* __restrict__ A, const bf16* __restrict__ Bt,
    const float* __restrict__ bias, const float* __restrict__ aux,
    bf16* __restrict__ vt,
    void* __restrict__ Cout, int M, int N, int K) {
  constexpr int WTM = BM / 2, WTN = BN / 2;
  constexpr int MT = WTM / 16, NT = WTN / 16;
  __shared__ bf16 As[BM * 64];
  __shared__ bf16 Bs[BN * 64];
  int tid = threadIdx.x;
  int wave = tid >> 6, lane = tid & 63;
  int wm = wave >> 1, wn = wave & 1;
  int m15 = lane & 15, q = lane >> 4;
  int m0 = blockIdx.y * BM, n0 = blockIdx.x * BN;
  int kspan = K / gridDim.z;
  int kbeg = blockIdx.z * kspan, kend = kbeg + kspan;

  f32x4 acc[MT][NT];
#pragma unroll
  for (int i = 0; i < MT; ++i)
#pragma unroll
    for (int j = 0; j < NT; ++j) acc[i][j] = (f32x4){0.f, 0.f, 0.f, 0.f};

  for (int k0 = kbeg; k0 < kend; k0 += 64) {
    // stage A and B: each lane DMAs 16B; LDS offset = c*16 bytes (= c*8 bf16)
#pragma unroll
    for (int it = 0; it < BM * 8 / 256; ++it) {
      int c = tid + it * 256;
      int row = c >> 3, cc = c & 7;
      gl2lds16(&A[(size_t)(m0 + row) * K + k0 + cc * 8], &As[c * 8]);
    }
#pragma unroll
    for (int it = 0; it < BN * 8 / 256; ++it) {
      int c = tid + it * 256;
      int row = c >> 3, cc = c & 7;
      gl2lds16(&Bt[(size_t)(n0 + row) * K + k0 + cc * 8], &Bs[c * 8]);
    }
    __syncthreads();
#pragma unroll
    for (int s = 0; s < 2; ++s) {
      bf16x8 af[MT], bfr[NT];
#pragma unroll
      for (int i = 0; i < MT; ++i)
        af[i] = *(const bf16x8*)&As[(wm * WTM + i * 16 + m15) * 64 + s * 32 + q * 8];
#pragma unroll
      for (int j = 0; j < NT; ++j)
        bfr[j] = *(const bf16x8*)&Bs[(wn * WTN + j * 16 + m15) * 64 + s * 32 + q * 8];
#pragma unroll
      for (int i = 0; i < MT; ++i)
#pragma unroll
        for (int j = 0; j < NT; ++j)
          acc[i][j] = __builtin_amdgcn_mfma_f32_16x16x32_bf16(af[i], bfr[j], acc[i][j], 0, 0, 0);
    }
    __syncthreads();
  }

#pragma unroll
  for (int i = 0; i < MT; ++i) {
#pragma unroll
    for (int j = 0; j < NT; ++j) {
      int col = n0 + wn * WTN + j * 16 + m15;
      if (EPI == 4) {
        if (col < 1536) {
#pragma unroll
          for (int r = 0; r < 4; ++r) {
            int row = m0 + wm * WTM + i * 16 + q * 4 + r;
            ((bf16*)Cout)[(size_t)row * 1536 + col] = __float2bfloat16(acc[i][j][r]);
          }
        } else {
          int row0 = m0 + wm * WTM + i * 16 + q * 4;
          int cl = col - 1536;
          int hh = cl >> 6, dd = cl & 63;
          int bb = row0 >> 9, tok = row0 & 511;
          bf16 pk[4];
#pragma unroll
          for (int r = 0; r < 4; ++r) pk[r] = __float2bfloat16(acc[i][j][r]);
          *(uint2*)&vt[((size_t)(bb * 12 + hh) * 64 + dd) * 512 + tok] = *(uint2*)pk;
        }
      } else if (EPI == 5) {
        float bv = (blockIdx.z == 0) ? bias[col] : 0.f;
#pragma unroll
        for (int r = 0; r < 4; ++r) {
          int row = m0 + wm * WTM + i * 16 + q * 4 + r;
          unsafeAtomicAdd(&((float*)Cout)[(size_t)row * N + col], acc[i][j][r] + bv);
        }
      } else {
        float bv = (EPI == 0) ? 0.f : bias[col];
#pragma unroll
        for (int r = 0; r < 4; ++r) {
          int row = m0 + wm * WTM + i * 16 + q * 4 + r;
          float v = acc[i][j][r] + bv;
          if (EPI == 2) v = tanhf(v);
          if (EPI == 3) v += aux[(size_t)(row & 511) * N + col];
          if (EPI == 0 || EPI == 2)
            ((bf16*)Cout)[(size_t)row * N + col] = __float2bfloat16(v);
          else
            ((float*)Cout)[(size_t)row * N + col] = v;
        }
      }
    }
  }
}

// ---------------------------------------------------------------------------
// MFMA attention. Block = (b*12+h, 32-query tile), 128 thr = 2 waves.
// KVs staged via global_load_lds, unpadded stride 64.
// ---------------------------------------------------------------------------
__global__ __launch_bounds__(128) void attn_mfma(const bf16* __restrict__ qk,
                                                 const bf16* __restrict__ Vt,
                                                 bf16* __restrict__ o) {
  constexpr int PS = 520;  // P stride: 1040 B, 16B-aligned, banks shift by 4
  __shared__ bf16 KVs[64 * 64];
  __shared__ bf16 P[32 * PS];
  int bh = blockIdx.x;
  int b = bh / 12, hh = bh % 12;
  int q0 = blockIdx.y * 32;
  int tid = threadIdx.x;
  int wave = tid >> 6, lane = tid & 63;
  int n15 = lane & 15, quad = lane >> 4;
  const bf16* qkb = qk + (size_t)b * 512 * 1536;
  int ql = wave * 16 + n15;

  const bf16* qp = qkb + (size_t)(q0 + ql) * 1536 + hh * 64 + quad * 8;
  bf16x8 qf0 = *(const bf16x8*)qp;
  bf16x8 qf1 = *(const bf16x8*)(qp + 32);

  f32x4 S[32];
#pragma unroll
  for (int i = 0; i < 32; ++i) S[i] = (f32x4){0.f, 0.f, 0.f, 0.f};

  const bf16* kbase = qkb + 768 + hh * 64;
#pragma unroll
  for (int kc = 0; kc < 8; ++kc) {
    __syncthreads();
#pragma unroll
    for (int it = 0; it < 4; ++it) {
      int c = tid + it * 128;
      int r = c >> 3, cc = c & 7;
      gl2lds16(&kbase[(size_t)(kc * 64 + r) * 1536 + cc * 8], &KVs[c * 8]);
    }
    __syncthreads();
#pragma unroll
    for (int t = 0; t < 4; ++t) {
      int idx = kc * 4 + t;
      bf16x8 a0 = *(const bf16x8*)&KVs[(t * 16 + n15) * 64 + quad * 8];
      bf16x8 a1 = *(const bf16x8*)&KVs[(t * 16 + n15) * 64 + 32 + quad * 8];
      S[idx] = __builtin_amdgcn_mfma_f32_16x16x32_bf16(a0, qf0, S[idx], 0, 0, 0);
      S[idx] = __builtin_amdgcn_mfma_f32_16x16x32_bf16(a1, qf1, S[idx], 0, 0, 0);
    }
  }

  float mx = -1e30f;
#pragma unroll
  for (int i = 0; i < 32; ++i)
#pragma unroll
    for (int r = 0; r < 4; ++r) { S[i][r] *= 0.125f; mx = fmaxf(mx, S[i][r]); }
  mx = fmaxf(mx, __shfl_xor(mx, 16));
  mx = fmaxf(mx, __shfl_xor(mx, 32));
  float sum = 0.f;
#pragma unroll
  for (int i = 0; i < 32; ++i)
#pragma unroll
    for (int r = 0; r < 4; ++r) { float e = __expf(S[i][r] - mx); S[i][r] = e; sum += e; }
  sum += __shfl_xor(sum, 16);
  sum += __shfl_xor(sum, 32);
  float inv = 1.f / sum;

#pragma unroll
  for (int i = 0; i < 32; ++i) {
    bf16 pk[4];
#pragma unroll
    for (int r = 0; r < 4; ++r) pk[r] = __float2bfloat16(S[i][r] * inv);
    *(uint2*)&P[(size_t)ql * PS + i * 16 + quad * 4] = *(uint2*)pk;
  }

  f32x4 oacc[4];
#pragma unroll
  for (int dt = 0; dt < 4; ++dt) oacc[dt] = (f32x4){0.f, 0.f, 0.f, 0.f};
  const bf16* vtb = Vt + (size_t)bh * 64 * 512;
  for (int kc = 0; kc < 8; ++kc) {
    __syncthreads();
#pragma unroll
    for (int it = 0; it < 4; ++it) {
      int c = tid + it * 128;
      int r = c >> 3, cc = c & 7;
      gl2lds16(&vtb[(size_t)r * 512 + kc * 64 + cc * 8], &KVs[c * 8]);
    }
    __syncthreads();
    bf16x8 p0 = *(const bf16x8*)&P[(size_t)ql * PS + kc * 64 + quad * 8];
    bf16x8 p1 = *(const bf16x8*)&P[(size_t)ql * PS + kc * 64 + 32 + quad * 8];
#pragma unroll
    for (int dt = 0; dt < 4; ++dt) {
      bf16x8 v0 = *(const bf16x8*)&KVs[(dt * 16 + n15) * 64 + quad * 8];
      bf16x8 v1 = *(const bf16x8*)&KVs[(dt * 16 + n15) * 64 + 32 + quad * 8];
      oacc[dt] = __builtin_amdgcn_mfma_f32_16x16x32_bf16(p0, v0, oacc[dt], 0, 0, 0);
      oacc[dt] = __builtin_amdgcn_mfma_f32_16x16x32_bf16(p1, v1, oacc[dt], 0, 0, 0);
    }
  }

#pragma unroll
  for (int dt = 0; dt < 4; ++dt)
#pragma unroll
    for (int r = 0; r < 4; ++r) {
      int tok = q0 + wave * 16 + quad * 4 + r;
      o[((size_t)b * 512 + tok) * 768 + hh * 64 + dt * 16 + n15] =
          __float2bfloat16(oacc[dt][r]);
    }
}

// ---------------------------------------------------------------------------
extern "C" void kernel_launch(void* const* d_in, const int* in_sizes, int n_in,
                              void* d_out, int out_size, void* d_ws, size_t ws_size,
                              hipStream_t stream) {
  const float* volume = (const float*)d_in[0];
  const float* conv_w = (const float*)d_in[1];
  const float* conv_b = (const float*)d_in[2];
  const float* pos    = (const float*)d_in[3];
  const float* ln1w   = (const float*)d_in[4];
  const float* ln1b   = (const float*)d_in[5];
  const float* wqkv   = (const float*)d_in[6];
  const float* wo     = (const float*)d_in[7];
  const float* bo     = (const float*)d_in[8];
  const float* ln2w   = (const float*)d_in[9];
  const float* ln2b   = (const float*)d_in[10];
  const float* w1     = (const float*)d_in[11];
  const float* b1     = (const float*)d_in[12];
  const float* w2     = (const float*)d_in[13];
  const float* b2     = (const float*)d_in[14];
  const float* lnfw   = (const float*)d_in[15];
  const float* lnfb   = (const float*)d_in[16];

  // ws layout (~73 MB of ~268 MB)
  char* w = (char*)d_ws;
  float* x    = (float*)(w + 0);           // fp32 residual [1024][768]
  bf16* h     = (bf16*)(w + 3145728);      // ln out [1024][768]
  bf16* qk    = (bf16*)(w + 4718592);      // Q|K [1024][1536]; aliases patchA
  bf16* patchA= qk;                        // im2col [1024][512]
  bf16* Vt    = (bf16*)(w + 7864320);      // V^T [24][64][512]
  bf16* oact  = (bf16*)(w + 9437184);      // attn-o / mlp act [1024][3072]
  bf16* cwb   = (bf16*)(w + 15728640);     // conv_w bf16 [768][512]
  bf16* tqkv  = (bf16*)(w + 16515072);     // 4 x [2304][768]
  bf16* two   = (bf16*)(w + 30670848);     // 4 x [768][768]
  bf16* t1    = (bf16*)(w + 35389440);     // 4 x [3072][768]
  bf16* t2    = (bf16*)(w + 54263808);     // 4 x [768][3072]

  convert_kernel<<<384, 256, 0, stream>>>(conv_w, cwb, 768 * 512);
  im2col_kernel<<<1024, 256, 0, stream>>>(volume, patchA);
  transpose_all<<<dim3(1728, 4), 256, 0, stream>>>(wqkv, wo, w1, w2, tqkv, two, t1, t2);
  mfma_gemm<64, 64, 3><<<dim3(12, 16), 256, 0, stream>>>(
      patchA, cwb, conv_b, pos, nullptr, x, 1024, 768, 512);

  for (int L = 0; L < 4; ++L) {
    ln_kernel<bf16><<<1024, 256, 0, stream>>>(x, ln1w + L * 768, ln1b + L * 768, h);
    mfma_gemm<64, 64, 4><<<dim3(36, 16), 256, 0, stream>>>(
        h, tqkv + (size_t)L * 768 * 2304, nullptr, nullptr, Vt, qk, 1024, 2304, 768);
    attn_mfma<<<dim3(24, 16), 128, 0, stream>>>(qk, Vt, oact);
    mfma_gemm<64, 64, 5><<<dim3(12, 16, 2), 256, 0, stream>>>(
        oact, two + (size_t)L * 768 * 768, bo + L * 768, nullptr, nullptr, x, 1024, 768, 768);
    ln_kernel<bf16><<<1024, 256, 0, stream>>>(x, ln2w + L * 768, ln2b + L * 768, h);
    mfma_gemm<64, 64, 2><<<dim3(48, 16), 256, 0, stream>>>(
        h, t1 + (size_t)L * 768 * 3072, b1 + L * 3072, nullptr, nullptr, oact, 1024, 3072, 768);
    mfma_gemm<64, 64, 5><<<dim3(12, 16, 4), 256, 0, stream>>>(
        oact, t2 + (size_t)L * 768 * 3072, b2 + L * 768, nullptr, nullptr, x, 1024, 768, 3072);
  }

  ln_kernel<float><<<1024, 256, 0, stream>>>(x, lnfw, lnfb, (float*)d_out);
}